// Round 6
// baseline (124.633 us; speedup 1.0000x reference)
//
#include <hip/hip_runtime.h>
#include <hip/hip_fp16.h>

typedef float    f32x2 __attribute__((ext_vector_type(2)));
typedef float    f32x4 __attribute__((ext_vector_type(4)));
typedef _Float16 f16x4 __attribute__((ext_vector_type(4)));

#define NA    128   // batches
#define NPTS  256   // points per path
#define DD    16    // feature dim
#define MMI   255   // increments per axis
#define NSTEP 318   // MMI + 63 wavefront steps
#define GR    320   // padded skew rows per problem (318 used, +2 pad)
#define GHPP  (GR * 256)            // halves per problem = 81920
#define G_BYTES ((size_t)3 * NA * GHPP * 2)   // ~63 MB

// whole-wave shift-down-by-1 via DPP; lane 0 keeps `boundary`.
__device__ __forceinline__ float wave_shr1(float x, float boundary) {
    int r = __builtin_amdgcn_update_dpp(
        __builtin_bit_cast(int, boundary),
        __builtin_bit_cast(int, x),
        0x138 /* wave_shr:1 */, 0xF, 0xF, false);
    return __builtin_bit_cast(float, r);
}

// ---------------- kernel 1: Gram increments via MFMA, skewed fp16 ----------
// One block (256 thr = 4 waves) per problem. g = dU . dV^T, K=16, computed as
// 256 16x16 tiles with v_mfma_f32_16x16x16f16 (A = dV tile so each lane holds
// 4 consecutive cols of one row -> packed 8B skewed store).
// Skew: G[srow = r + c/4][c] = g[r][c]; cells with r<0 / r>255 are zero.
__global__ __launch_bounds__(256)
void sig_gram(const float* __restrict__ X, const float* __restrict__ Y,
              __half* __restrict__ G) {
    const int pb   = blockIdx.x;
    const int pair = pb >> 7;     // 0: XX, 1: YY, 2: XY
    const int a    = pb & 127;
    const float* U = (pair == 1) ? Y : X;   // rows of g
    const float* V = (pair == 0) ? X : Y;   // cols of g
    U += (size_t)a * (NPTS * DD);
    V += (size_t)a * (NPTS * DD);

    __shared__ _Float16 dUh[256][16];   // row 255 = 0
    __shared__ _Float16 dVh[256][16];

    const int tid = threadIdx.x;

    // ---- stage fp16 increments; thread t -> point-row t ----
    {
        float du[16], dv[16];
        if (tid < MMI) {
            const float4* Ua = (const float4*)(U + (size_t)tid * DD);
            const float4* Va = (const float4*)(V + (size_t)tid * DD);
            #pragma unroll
            for (int q = 0; q < 4; ++q) {
                float4 lo = Ua[q], hi = Ua[q + 4];
                du[4*q+0] = hi.x - lo.x; du[4*q+1] = hi.y - lo.y;
                du[4*q+2] = hi.z - lo.z; du[4*q+3] = hi.w - lo.w;
                lo = Va[q]; hi = Va[q + 4];
                dv[4*q+0] = hi.x - lo.x; dv[4*q+1] = hi.y - lo.y;
                dv[4*q+2] = hi.z - lo.z; dv[4*q+3] = hi.w - lo.w;
            }
        } else {
            #pragma unroll
            for (int k = 0; k < 16; ++k) { du[k] = 0.f; dv[k] = 0.f; }
        }
        #pragma unroll
        for (int k = 0; k < 16; ++k) {
            dUh[tid][k] = (_Float16)du[k];
            dVh[tid][k] = (_Float16)dv[k];
        }
    }

    // ---- zero the skew corners (rows 0..62 and 256..317, full rows) ----
    {
        const float4 z = make_float4(0.f, 0.f, 0.f, 0.f);
        float4* g0 = (float4*)(G + (size_t)pb * GHPP);           // 63*512B = 2016 f4
        float4* g2 = (float4*)(G + (size_t)pb * GHPP + 65536);   // 62*512B = 1984 f4
        for (int i = tid; i < 4000; i += 256) {
            if (i < 2016) g0[i] = z;
            else          g2[i - 2016] = z;
        }
    }

    __syncthreads();

    // ---- MFMA tiles: wave w owns col-tiles 4w..4w+3 ----
    const int l   = tid & 63;
    const int w   = tid >> 6;
    const int r15 = l & 15;
    const int q   = l >> 4;

    // A frags (dV side, M = c): A[m][k] = dVh[c0+m][k], lane m = l&15, k-quad q
    f16x4 A0 = *(const f16x4*)(&dVh[64*w +  0 + r15][4*q]);
    f16x4 A1 = *(const f16x4*)(&dVh[64*w + 16 + r15][4*q]);
    f16x4 A2 = *(const f16x4*)(&dVh[64*w + 32 + r15][4*q]);
    f16x4 A3 = *(const f16x4*)(&dVh[64*w + 48 + r15][4*q]);

    // store index (halves): srow = 16rt + 16w + 4j + r15 + q; col = 64w+16j+4q
    __half* Gp = G + (size_t)pb * GHPP + 4160*w + 256*r15 + 260*q;

    #pragma unroll 4
    for (int rt = 0; rt < 16; ++rt) {
        // B frag (dU side, N = r): B[k][n] = dUh[r0+n][k]
        f16x4 B = *(const f16x4*)(&dUh[16*rt + r15][4*q]);
        __half* Gr = Gp + 4096*rt;
        #pragma unroll
        for (int j = 0; j < 4; ++j) {
            f32x4 d = __builtin_amdgcn_mfma_f32_16x16x16f16(
                (j==0)?A0:(j==1)?A1:(j==2)?A2:A3, B,
                (f32x4){0.f, 0.f, 0.f, 0.f}, 0, 0, 0);
            __half2 h01 = __floats2half2_rn(d[0], d[1]);
            __half2 h23 = __floats2half2_rn(d[2], d[3]);
            uint2 wv;
            wv.x = __builtin_bit_cast(unsigned int, h01);
            wv.y = __builtin_bit_cast(unsigned int, h23);
            *(uint2*)(Gr + 1040*j) = wv;
        }
    }
}

// ---------------- kernel 2: slim PDE waves, 8 problems / block --------------
// 512 thr = 8 waves = 8 problems -> 2 waves per SIMD (hides the 4cy dep
// latency of a solo wave). 12-deep prefetch of the 512B skew rows.
__global__ __launch_bounds__(512)
void sig_pde2(const __half* __restrict__ G, float* __restrict__ out) {
    const int wid  = threadIdx.x >> 6;
    const int lane = threadIdx.x & 63;
    const int pid  = blockIdx.x * 8 + wid;
    const int pair = pid >> 7;
    const float w  = (pair == 2) ? (-2.0f / (float)NA) : (1.0f / (float)NA);

    const __half* gp = G + (size_t)pid * GHPP + 4 * lane;

    float kup0 = 1.f, kup1 = 1.f, kup2 = 1.f, kup3 = 1.f;
    float shnew = 1.f, shprev = 1.f;

    auto LD = [&](int i) { return *(const uint2*)(gp + i * 256); };

    auto STEP = [&](uint2 b) {
        float2 f01 = __half22float2(__builtin_bit_cast(__half2, b.x));
        float2 f23 = __half22float2(__builtin_bit_cast(__half2, b.y));
        f32x2 g01 = f32x2{f01.x, f01.y}, g23 = f32x2{f23.x, f23.y};
        f32x2 e01 = (g01 * g01) * f32x2{1.f/12.f, 1.f/12.f};
        f32x2 e23 = (g23 * g23) * f32x2{1.f/12.f, 1.f/12.f};
        f32x2 c1a = __builtin_elementwise_fma(g01, f32x2{0.5f,0.5f},
                                              f32x2{1.f,1.f}) + e01;
        f32x2 c1b = __builtin_elementwise_fma(g23, f32x2{0.5f,0.5f},
                                              f32x2{1.f,1.f}) + e23;
        f32x2 c2a = f32x2{1.f,1.f} - e01;
        f32x2 c2b = f32x2{1.f,1.f} - e23;

        const float left = shnew, upleft = shprev;
        const float pre0 = fmaf(kup0, c1a.x, -(upleft * c2a.x));
        const float pre1 = fmaf(kup1, c1a.y, -(kup0 * c2a.y));
        const float pre2 = fmaf(kup2, c1b.x, -(kup1 * c2b.x));
        const float pre3 = fmaf(kup3, c1b.y, -(kup2 * c2b.y));
        const float t0 = fmaf(left, c1a.x, pre0);
        const float t1 = fmaf(t0,   c1a.y, pre1);
        const float t2 = fmaf(t1,   c1b.x, pre2);
        const float t3 = fmaf(t2,   c1b.y, pre3);
        shprev = shnew;
        kup0 = t0; kup1 = t1; kup2 = t2; kup3 = t3;
        shnew = wave_shr1(t3, 1.0f);
    };

    // 12-deep prefetch; 318 = 12*26 + 6 (last full iter's loads are unused pad)
    uint2 b0=LD(0), b1=LD(1), b2=LD(2),  b3=LD(3),  b4=LD(4),  b5=LD(5),
          b6=LD(6), b7=LD(7), b8=LD(8),  b9=LD(9),  b10=LD(10), b11=LD(11);
    gp += 12 * 256;
    for (int it = 0; it < 26; ++it) {
        STEP(b0);  b0  = LD(0);
        STEP(b1);  b1  = LD(1);
        STEP(b2);  b2  = LD(2);
        STEP(b3);  b3  = LD(3);
        STEP(b4);  b4  = LD(4);
        STEP(b5);  b5  = LD(5);
        STEP(b6);  b6  = LD(6);
        STEP(b7);  b7  = LD(7);
        STEP(b8);  b8  = LD(8);
        STEP(b9);  b9  = LD(9);
        STEP(b10); b10 = LD(10);
        STEP(b11); b11 = LD(11);
        gp += 12 * 256;
    }
    STEP(b0); STEP(b1); STEP(b2); STEP(b3); STEP(b4); STEP(b5);

    // block-level reduction: 1 atomic per block
    __shared__ float psum[8];
    if (lane == 63) psum[wid] = w * kup2;   // K[255][255] = lane63 kup2
    __syncthreads();
    if (threadIdx.x == 0) {
        float s = psum[0] + psum[1] + psum[2] + psum[3]
                + psum[4] + psum[5] + psum[6] + psum[7];
        atomicAdd(out, s);
    }
}

// ---------------- fallback (R4 single-kernel, proven) ----------------------
__global__ __launch_bounds__(64)
void sig_pde(const float* __restrict__ X, const float* __restrict__ Y,
             float* __restrict__ out) {
    const int pid  = blockIdx.x;
    const int pair = pid >> 7;
    const int a    = pid & 127;
    const float* U = (pair == 1) ? Y : X;
    const float* V = (pair == 0) ? X : Y;
    const float  w = (pair == 2) ? (-2.0f / (float)NA) : (1.0f / (float)NA);
    U += (size_t)a * (NPTS * DD);
    V += (size_t)a * (NPTS * DD);
    __shared__ float dU[4][256][4];
    const int lane = threadIdx.x;
    const float4* U4 = (const float4*)U;
    #pragma unroll
    for (int i = 0; i < 16; ++i) {
        int t = lane + (i << 6);
        int qd = t >> 8, r = t & 255;
        float4 val = make_float4(0.f, 0.f, 0.f, 0.f);
        if (r < MMI) {
            float4 lo = U4[r * 4 + qd], hi = U4[r * 4 + 4 + qd];
            val = make_float4(hi.x - lo.x, hi.y - lo.y, hi.z - lo.z, hi.w - lo.w);
        }
        *(float4*)(&dU[qd][r][0]) = val;
    }
    f32x2 v[4][8];
    #pragma unroll
    for (int k = 0; k < 4; ++k) {
        int j = (lane << 2) + k;
        const bool valid = (j < MMI);
        const int jj = valid ? j : 0;
        const float2* Va = (const float2*)(V + (size_t)jj * DD);
        const float2* Vb = (const float2*)(V + (size_t)(jj + 1) * DD);
        #pragma unroll
        for (int q = 0; q < 8; ++q) {
            float2 lo = Va[q], hi = Vb[q];
            v[k][q] = valid ? f32x2{hi.x - lo.x, hi.y - lo.y} : f32x2{0.f, 0.f};
        }
    }
    __syncthreads();
    auto rowidx = [&](int s) {
        int rr = s - lane;
        return ((unsigned)rr < (unsigned)MMI) ? rr : 255;
    };
    auto load_row = [&](int s, f32x2* uu) {
        const float4* p = (const float4*)&dU[0][rowidx(s)][0];
        #pragma unroll
        for (int q = 0; q < 4; ++q) {
            float4 t = p[q << 8];
            uu[2 * q + 0] = f32x2{t.x, t.y};
            uu[2 * q + 1] = f32x2{t.z, t.w};
        }
    };
    float c1[4], c2[4];
    auto compute_c = [&](const f32x2* uu) {
        #pragma unroll
        for (int k = 0; k < 4; ++k) {
            f32x2 acc = uu[0] * v[k][0];
            #pragma unroll
            for (int q = 1; q < 8; ++q) acc += uu[q] * v[k][q];
            const float g = acc.x + acc.y;
            const float e = g * g * (1.0f / 12.0f);
            c1[k] = fmaf(0.5f, g, 1.0f) + e;
            c2[k] = 1.0f - e;
        }
    };
    float kup0 = 1.f, kup1 = 1.f, kup2 = 1.f, kup3 = 1.f;
    float shnew = 1.f, shprev = 1.f;
    auto step = [&]() {
        const float left = shnew, upleft = shprev;
        const float pre0 = fmaf(kup0, c1[0], -(upleft * c2[0]));
        const float pre1 = fmaf(kup1, c1[1], -(kup0 * c2[1]));
        const float pre2 = fmaf(kup2, c1[2], -(kup1 * c2[2]));
        const float pre3 = fmaf(kup3, c1[3], -(kup2 * c2[3]));
        const float t0 = fmaf(left, c1[0], pre0);
        const float t1 = fmaf(t0,   c1[1], pre1);
        const float t2 = fmaf(t1,   c1[2], pre2);
        const float t3 = fmaf(t2,   c1[3], pre3);
        shprev = shnew;
        kup0 = t0; kup1 = t1; kup2 = t2; kup3 = t3;
        shnew = wave_shr1(t3, 1.0f);
    };
    f32x2 bufA[8], bufB[8], bufC[8];
    {
        f32x2 t[8];
        load_row(0, t);
        compute_c(t);
    }
    load_row(1, bufA);
    load_row(2, bufB);
    for (int s = 0; s < NSTEP; s += 3) {
        load_row(s + 3, bufC); step(); compute_c(bufA);
        load_row(s + 4, bufA); step(); compute_c(bufB);
        load_row(s + 5, bufB); step(); compute_c(bufC);
    }
    if (lane == 63) atomicAdd(out, w * kup2);
}

extern "C" void kernel_launch(void* const* d_in, const int* in_sizes, int n_in,
                              void* d_out, int out_size, void* d_ws, size_t ws_size,
                              hipStream_t stream) {
    const float* X = (const float*)d_in[0];
    const float* Y = (const float*)d_in[1];
    float* out = (float*)d_out;
    hipMemsetAsync(out, 0, sizeof(float), stream);
    if (ws_size >= G_BYTES) {
        __half* G = (__half*)d_ws;
        sig_gram<<<dim3(3 * NA), dim3(256), 0, stream>>>(X, Y, G);
        sig_pde2<<<dim3(3 * NA / 8), dim3(512), 0, stream>>>(G, out);
    } else {
        sig_pde<<<dim3(3 * NA), dim3(64), 0, stream>>>(X, Y, out);
    }
}

// Round 7
// 100.203 us; speedup vs baseline: 1.2438x; 1.2438x over previous
//
#include <hip/hip_runtime.h>
#include <hip/hip_fp16.h>

typedef float f32x2 __attribute__((ext_vector_type(2)));

#define NA    128
#define NPTS  256
#define DD    16
#define MMI   255    // valid inc rows/cols 0..254; index 255 = zero row
#define NSTEP 318    // 255 + 63 wavefront steps
#define RING  96     // LDS ring slots (skew rows), fp16

// whole-wave shift-down-by-1 via DPP; lane 0 keeps `boundary`.
__device__ __forceinline__ float wave_shr1(float x, float boundary) {
    int r = __builtin_amdgcn_update_dpp(
        __builtin_bit_cast(int, boundary),
        __builtin_bit_cast(int, x),
        0x138 /* wave_shr:1 */, 0xF, 0xF, false);
    return __builtin_bit_cast(float, r);
}

// One block (256 thr = 4 waves) per (pair, batch) problem.
// Wave 0: skewed-wavefront PDE consumer (lane l owns cols 4l..4l+3, step s
//         processes row r = s - l), reading fp16 skew-rows from the LDS ring.
// Waves 1-3: producers. Whole wave computes one g-row r (uniform dU[r]
//         broadcast from LDS, per-lane dV columns in registers) and writes
//         the fp16 values scattered to skew slots (r + lane) % 96.
// Boundary handling: ring pre-zeroed; rows r>=255 written as zeros; g=0 =>
// c1=c2=1 identity keeps K=1 outside the active triangle (proven R4-R6).
__global__ __launch_bounds__(256)
void sig_fused(const float* __restrict__ X, const float* __restrict__ Y,
               float* __restrict__ out) {
    const int pid  = blockIdx.x;
    const int pair = pid >> 7;     // 0: XX, 1: YY, 2: XY
    const int a    = pid & 127;
    const float* U = (pair == 1) ? Y : X;   // g rows
    const float* V = (pair == 0) ? X : Y;   // g cols
    const float  w = (pair == 2) ? (-2.0f / (float)NA) : (1.0f / (float)NA);
    U += (size_t)a * (NPTS * DD);
    V += (size_t)a * (NPTS * DD);

    __shared__ float  dU[256][16];        // 16 KB, row 255 = 0
    __shared__ __half ring[RING][256];    // 48 KB

    const int tid  = threadIdx.x;
    const int wid  = tid >> 6;
    const int lane = tid & 63;

    // ---- stage dU: thread handles 16B chunks sequentially (coalesced
    // global reads, conflict-free sequential LDS writes) ----
    {
        const float4* U4 = (const float4*)U;
        #pragma unroll
        for (int m = 0; m < 4; ++m) {
            int idx = tid + 256 * m;            // 0..1023
            int row = idx >> 2;
            float4 val = make_float4(0.f, 0.f, 0.f, 0.f);
            if (row < MMI) {
                float4 lo = U4[idx];            // U4[row*4 + q]
                float4 hi = U4[idx + 4];        // row+1
                val = make_float4(hi.x - lo.x, hi.y - lo.y,
                                  hi.z - lo.z, hi.w - lo.w);
            }
            *(float4*)(&dU[row][(idx & 3) * 4]) = val;
        }
    }
    // ---- zero the ring (covers all r<0 cells permanently) ----
    {
        float4* rp = (float4*)&ring[0][0];      // 48KB = 3072 float4
        const float4 z = make_float4(0.f, 0.f, 0.f, 0.f);
        #pragma unroll
        for (int m = 0; m < 12; ++m) rp[tid + 256 * m] = z;
    }

    // ---- producer dV registers: cols 4*lane .. 4*lane+3 ----
    f32x2 dv[4][8];
    if (wid != 0) {
        #pragma unroll
        for (int k = 0; k < 4; ++k) {
            int j = 4 * lane + k;
            const bool valid = (j < MMI);
            const int jj = valid ? j : 0;
            const float2* Va = (const float2*)(V + (size_t)jj * DD);
            const float2* Vb = (const float2*)(V + (size_t)(jj + 1) * DD);
            #pragma unroll
            for (int q = 0; q < 8; ++q) {
                float2 lo = Va[q], hi = Vb[q];
                dv[k][q] = valid ? f32x2{hi.x - lo.x, hi.y - lo.y}
                                 : f32x2{0.f, 0.f};
            }
        }
    }
    __syncthreads();

    // ---- producer: compute g-row r, write fp16 to skew slots ----
    auto produce = [&](int r) {
        int slot = r + lane;                    // < 318 + 63
        slot -= (slot >= 96)  ? 96 : 0;
        slot -= (slot >= 96)  ? 96 : 0;
        slot -= (slot >= 96)  ? 96 : 0;
        uint2 wv = make_uint2(0u, 0u);
        if (r < MMI) {
            const float4* up4 = (const float4*)&dU[r][0];   // uniform: broadcast
            float4 u0 = up4[0], u1 = up4[1], u2 = up4[2], u3 = up4[3];
            f32x2 uu[8] = {
                f32x2{u0.x, u0.y}, f32x2{u0.z, u0.w},
                f32x2{u1.x, u1.y}, f32x2{u1.z, u1.w},
                f32x2{u2.x, u2.y}, f32x2{u2.z, u2.w},
                f32x2{u3.x, u3.y}, f32x2{u3.z, u3.w}};
            f32x2 a0 = uu[0] * dv[0][0];
            f32x2 a1 = uu[0] * dv[1][0];
            f32x2 a2 = uu[0] * dv[2][0];
            f32x2 a3 = uu[0] * dv[3][0];
            #pragma unroll
            for (int q = 1; q < 8; ++q) {
                a0 = __builtin_elementwise_fma(uu[q], dv[0][q], a0);
                a1 = __builtin_elementwise_fma(uu[q], dv[1][q], a1);
                a2 = __builtin_elementwise_fma(uu[q], dv[2][q], a2);
                a3 = __builtin_elementwise_fma(uu[q], dv[3][q], a3);
            }
            __half2 h01 = __floats2half2_rn(a0.x + a0.y, a1.x + a1.y);
            __half2 h23 = __floats2half2_rn(a2.x + a2.y, a3.x + a3.y);
            wv.x = __builtin_bit_cast(unsigned int, h01);
            wv.y = __builtin_bit_cast(unsigned int, h23);
        }
        *(uint2*)(&ring[slot][4 * lane]) = wv;
    };

    // ---- consumer state ----
    float kup0 = 1.f, kup1 = 1.f, kup2 = 1.f, kup3 = 1.f;
    float shnew = 1.f, shprev = 1.f;

    auto STEP = [&](uint2 b) {
        float2 f01 = __half22float2(__builtin_bit_cast(__half2, b.x));
        float2 f23 = __half22float2(__builtin_bit_cast(__half2, b.y));
        f32x2 g01 = f32x2{f01.x, f01.y}, g23 = f32x2{f23.x, f23.y};
        f32x2 e01 = (g01 * g01) * f32x2{1.f/12.f, 1.f/12.f};
        f32x2 e23 = (g23 * g23) * f32x2{1.f/12.f, 1.f/12.f};
        f32x2 c1a = __builtin_elementwise_fma(g01, f32x2{0.5f, 0.5f},
                                              f32x2{1.f, 1.f}) + e01;
        f32x2 c1b = __builtin_elementwise_fma(g23, f32x2{0.5f, 0.5f},
                                              f32x2{1.f, 1.f}) + e23;
        f32x2 c2a = f32x2{1.f, 1.f} - e01;
        f32x2 c2b = f32x2{1.f, 1.f} - e23;
        const float left = shnew, upleft = shprev;
        const float pre0 = fmaf(kup0, c1a.x, -(upleft * c2a.x));
        const float pre1 = fmaf(kup1, c1a.y, -(kup0 * c2a.y));
        const float pre2 = fmaf(kup2, c1b.x, -(kup1 * c2b.x));
        const float pre3 = fmaf(kup3, c1b.y, -(kup2 * c2b.y));
        const float t0 = fmaf(left, c1a.x, pre0);
        const float t1 = fmaf(t0,   c1a.y, pre1);
        const float t2 = fmaf(t1,   c1b.x, pre2);
        const float t3 = fmaf(t2,   c1b.y, pre3);
        shprev = shnew;
        kup0 = t0; kup1 = t1; kup2 = t2; kup3 = t3;
        shnew = wave_shr1(t3, 1.0f);
    };

    // ---- prologue: produce skew rows 0..15 ----
    if (wid != 0) {
        for (int i = wid - 1; i < 16; i += 3) produce(i);
    }
    __syncthreads();

    // ---- 19 full phases: consume steps [16p,16p+16), produce rows
    //      [16p+16, 16p+32) (clipped to < 318). Slot ranges are disjoint. ----
    for (int ph = 0; ph < 19; ++ph) {
        if (wid == 0) {
            int slot0 = (16 * ph) % 96;
            uint2 gb[16];
            #pragma unroll
            for (int i = 0; i < 16; ++i) {
                int sl = slot0 + i;
                sl -= (sl >= 96) ? 96 : 0;
                gb[i] = *(const uint2*)(&ring[sl][4 * lane]);
            }
            #pragma unroll
            for (int i = 0; i < 16; ++i) STEP(gb[i]);
        } else {
            for (int i = wid - 1; i < 16; i += 3) {
                int r = 16 * ph + 16 + i;
                if (r < NSTEP) produce(r);
            }
        }
        __syncthreads();
    }

    // ---- tail: steps 304..317 (14), all rows already produced ----
    if (wid == 0) {
        const int slot0 = 304 % 96;   // 16
        uint2 gb[14];
        #pragma unroll
        for (int i = 0; i < 14; ++i) {
            int sl = slot0 + i;
            sl -= (sl >= 96) ? 96 : 0;
            gb[i] = *(const uint2*)(&ring[sl][4 * lane]);
        }
        #pragma unroll
        for (int i = 0; i < 14; ++i) STEP(gb[i]);
        // K[255][255] lives in lane 63's kup2 (col j = 4*63+2+1 = 255)
        if (lane == 63) atomicAdd(out, w * kup2);
    }
}

extern "C" void kernel_launch(void* const* d_in, const int* in_sizes, int n_in,
                              void* d_out, int out_size, void* d_ws, size_t ws_size,
                              hipStream_t stream) {
    const float* X = (const float*)d_in[0];
    const float* Y = (const float*)d_in[1];
    float* out = (float*)d_out;
    hipMemsetAsync(out, 0, sizeof(float), stream);
    sig_fused<<<dim3(3 * NA), dim3(256), 0, stream>>>(X, Y, out);
}

// Round 9
// 91.088 us; speedup vs baseline: 1.3683x; 1.1001x over previous
//
#include <hip/hip_runtime.h>
#include <hip/hip_fp16.h>

typedef float    f32x2 __attribute__((ext_vector_type(2)));
typedef _Float16 h16x2 __attribute__((ext_vector_type(2)));

#define NA    128
#define NPTS  256
#define DD    16
#define MMI   255    // valid inc rows/cols 0..254
#define NSTEP 318    // 255 + 63 wavefront steps
#define RINGN 128    // LDS ring slots (power of 2)
#define PH    32     // steps per phase

// whole-wave shift-down-by-1 via DPP; lane 0 keeps `boundary`.
__device__ __forceinline__ float wave_shr1(float x, float boundary) {
    int r = __builtin_amdgcn_update_dpp(
        __builtin_bit_cast(int, boundary),
        __builtin_bit_cast(int, x),
        0x138 /* wave_shr:1 */, 0xF, 0xF, false);
    return __builtin_bit_cast(float, r);
}

// fp16x2 dot with f32 accumulate (v_dot2_f32_f16), guarded fallback
__device__ __forceinline__ float fdot2h(unsigned int a, unsigned int b, float c) {
#if __has_builtin(__builtin_amdgcn_fdot2)
    return __builtin_amdgcn_fdot2(__builtin_bit_cast(h16x2, a),
                                  __builtin_bit_cast(h16x2, b), c, false);
#else
    h16x2 ha = __builtin_bit_cast(h16x2, a), hb = __builtin_bit_cast(h16x2, b);
    return c + (float)ha.x * (float)hb.x + (float)ha.y * (float)hb.y;
#endif
}

// pack 2 f32 -> half2 bits
__device__ __forceinline__ unsigned int pkh2(float a, float b) {
#if __has_builtin(__builtin_amdgcn_cvt_pkrtz)
    return __builtin_bit_cast(unsigned int, __builtin_amdgcn_cvt_pkrtz(a, b));
#else
    h16x2 h = {(_Float16)a, (_Float16)b};
    return __builtin_bit_cast(unsigned int, h);
#endif
}

// One block (4 waves) per (pair, batch) problem.
// Wave 0 = PDE consumer (skewed wavefront, lane l owns cols 4l..4l+3, step s
//   reads skew-slot s & 127: one ds_read_b64 per step).
// Waves 1-3 = producers: row r of g via v_dot2_f32_f16 (fp16 dU broadcast row
//   + fp16 dV column regs), write fp16 skew slot (r+lane)&127.
// Boundaries: ring pre-zeroed, rows >= 255 written as zeros; g=0 => c1=c2=1
// identity keeps K=1 outside the active triangle (proven R4-R7).
// Phase p: consumer eats steps [32p,32p+32), producers fill rows [32p+32,32p+64);
// slot spans 32 + 95 = 127 <= 128 -> disjoint (same argument as R7's 95<=96).
__global__ __launch_bounds__(256)
void sig_fused(const float* __restrict__ X, const float* __restrict__ Y,
               float* __restrict__ out) {
    const int pid  = blockIdx.x;
    const int pair = pid >> 7;     // 0: XX, 1: YY, 2: XY
    const int a    = pid & 127;
    const float* U = (pair == 1) ? Y : X;   // g rows
    const float* V = (pair == 0) ? X : Y;   // g cols
    const float  w = (pair == 2) ? (-2.0f / (float)NA) : (1.0f / (float)NA);
    U += (size_t)a * (NPTS * DD);
    V += (size_t)a * (NPTS * DD);

    __shared__ unsigned short dUh[256][16];     // 8 KB fp16 (row 255 = 0)
    __shared__ unsigned short ring[RINGN][256]; // 64 KB fp16

    const int tid  = threadIdx.x;
    const int wid  = tid >> 6;
    const int lane = tid & 63;

    // ---- stage dUh = fp16(diff(U)); thread t -> row t ----
    {
        float du[16];
        if (tid < MMI) {
            const float4* Ua = (const float4*)(U + (size_t)tid * DD);
            #pragma unroll
            for (int q = 0; q < 4; ++q) {
                float4 lo = Ua[q], hi = Ua[q + 4];
                du[4*q+0] = hi.x - lo.x; du[4*q+1] = hi.y - lo.y;
                du[4*q+2] = hi.z - lo.z; du[4*q+3] = hi.w - lo.w;
            }
        } else {
            #pragma unroll
            for (int k = 0; k < 16; ++k) du[k] = 0.f;
        }
        uint4 lo4, hi4;
        lo4.x = pkh2(du[0],  du[1]);  lo4.y = pkh2(du[2],  du[3]);
        lo4.z = pkh2(du[4],  du[5]);  lo4.w = pkh2(du[6],  du[7]);
        hi4.x = pkh2(du[8],  du[9]);  hi4.y = pkh2(du[10], du[11]);
        hi4.z = pkh2(du[12], du[13]); hi4.w = pkh2(du[14], du[15]);
        *(uint4*)(&dUh[tid][0]) = lo4;
        *(uint4*)(&dUh[tid][8]) = hi4;
    }
    // ---- zero ring (covers all r<0 cells until legitimately overwritten) ----
    {
        const uint4 z = {0u, 0u, 0u, 0u};
        uint4* rp = (uint4*)&ring[0][0];        // 4096 uint4
        #pragma unroll
        for (int m = 0; m < 16; ++m) rp[tid + 256*m] = z;
    }

    // ---- producer dV columns as packed half2 registers ----
    unsigned int dv2[4][8];
    if (wid != 0) {
        #pragma unroll
        for (int k = 0; k < 4; ++k) {
            int j = 4*lane + k;
            const bool valid = (j < MMI);
            const int jj = valid ? j : 0;
            const float2* Va = (const float2*)(V + (size_t)jj * DD);
            const float2* Vb = (const float2*)(V + (size_t)(jj + 1) * DD);
            #pragma unroll
            for (int q = 0; q < 8; ++q) {
                float2 lo = Va[q], hi = Vb[q];
                float dx = valid ? hi.x - lo.x : 0.f;
                float dy = valid ? hi.y - lo.y : 0.f;
                dv2[k][q] = pkh2(dx, dy);
            }
        }
    }
    __syncthreads();

    // ---- producer: g-row r -> fp16 skew slot ----
    auto produce = [&](int r) {
        uint2 wv = make_uint2(0u, 0u);
        if (r < MMI) {
            const uint2* du2 = (const uint2*)&dUh[r][0];   // uniform broadcast
            uint2 q0 = du2[0], q1 = du2[1], q2 = du2[2], q3 = du2[3];
            unsigned int dh[8] = {q0.x, q0.y, q1.x, q1.y, q2.x, q2.y, q3.x, q3.y};
            float a0 = 0.f, a1 = 0.f, a2 = 0.f, a3 = 0.f;
            #pragma unroll
            for (int q = 0; q < 8; ++q) {
                a0 = fdot2h(dh[q], dv2[0][q], a0);
                a1 = fdot2h(dh[q], dv2[1][q], a1);
                a2 = fdot2h(dh[q], dv2[2][q], a2);
                a3 = fdot2h(dh[q], dv2[3][q], a3);
            }
            wv.x = pkh2(a0, a1);
            wv.y = pkh2(a2, a3);
        }
        *(uint2*)(&ring[(r + lane) & (RINGN - 1)][4*lane]) = wv;
    };

    // ---- consumer state & step ----
    float kup0 = 1.f, kup1 = 1.f, kup2 = 1.f, kup3 = 1.f;
    float shnew = 1.f, shprev = 1.f;

    auto STEP = [&](uint2 b) {
        float2 f01 = __half22float2(__builtin_bit_cast(__half2, b.x));
        float2 f23 = __half22float2(__builtin_bit_cast(__half2, b.y));
        f32x2 g01 = f32x2{f01.x, f01.y}, g23 = f32x2{f23.x, f23.y};
        f32x2 e01 = (g01 * g01) * f32x2{1.f/12.f, 1.f/12.f};
        f32x2 e23 = (g23 * g23) * f32x2{1.f/12.f, 1.f/12.f};
        f32x2 c1a = __builtin_elementwise_fma(g01, f32x2{0.5f, 0.5f},
                                              f32x2{1.f, 1.f}) + e01;
        f32x2 c1b = __builtin_elementwise_fma(g23, f32x2{0.5f, 0.5f},
                                              f32x2{1.f, 1.f}) + e23;
        f32x2 c2a = f32x2{1.f, 1.f} - e01;
        f32x2 c2b = f32x2{1.f, 1.f} - e23;
        const float left = shnew, upleft = shprev;
        const float pre0 = fmaf(kup0, c1a.x, -(upleft * c2a.x));
        const float pre1 = fmaf(kup1, c1a.y, -(kup0 * c2a.y));
        const float pre2 = fmaf(kup2, c1b.x, -(kup1 * c2b.x));
        const float pre3 = fmaf(kup3, c1b.y, -(kup2 * c2b.y));
        const float t0 = fmaf(left, c1a.x, pre0);
        const float t1 = fmaf(t0,   c1a.y, pre1);
        const float t2 = fmaf(t1,   c1b.x, pre2);
        const float t3 = fmaf(t2,   c1b.y, pre3);
        shprev = shnew;
        kup0 = t0; kup1 = t1; kup2 = t2; kup3 = t3;
        shnew = wave_shr1(t3, 1.0f);
    };

    const unsigned short* rlane = &ring[0][4*lane];

    // ---- prologue: rows 0..31 ----
    if (wid != 0) {
        for (int r = wid - 1; r < PH; r += 3) produce(r);
    }
    __syncthreads();

    // ---- 9 full phases ----
    for (int ph = 0; ph < 9; ++ph) {
        if (wid == 0) {
            const unsigned short* rp = rlane + ((PH * ph) & (RINGN - 1)) * 256;
            uint2 A[8], B[8];
            #pragma unroll
            for (int i = 0; i < 8; ++i) A[i] = *(const uint2*)(rp + i * 256);
            #pragma unroll
            for (int i = 0; i < 8; ++i) B[i] = *(const uint2*)(rp + (8 + i) * 256);
            #pragma unroll
            for (int i = 0; i < 8; ++i) STEP(A[i]);
            #pragma unroll
            for (int i = 0; i < 8; ++i) A[i] = *(const uint2*)(rp + (16 + i) * 256);
            #pragma unroll
            for (int i = 0; i < 8; ++i) STEP(B[i]);
            #pragma unroll
            for (int i = 0; i < 8; ++i) B[i] = *(const uint2*)(rp + (24 + i) * 256);
            #pragma unroll
            for (int i = 0; i < 8; ++i) STEP(A[i]);
            #pragma unroll
            for (int i = 0; i < 8; ++i) STEP(B[i]);
        } else {
            int rend = PH * ph + 2 * PH;
            if (rend > NSTEP) rend = NSTEP;
            for (int r = PH * ph + PH + (wid - 1); r < rend; r += 3) produce(r);
        }
        __syncthreads();
    }

    // ---- tail: steps 288..317 (30 steps), base slot (288 & 127) = 32 ----
    if (wid == 0) {
        const unsigned short* rp = rlane + ((PH * 9) & (RINGN - 1)) * 256;
        uint2 A[8], B[8];
        #pragma unroll
        for (int i = 0; i < 8; ++i) A[i] = *(const uint2*)(rp + i * 256);
        #pragma unroll
        for (int i = 0; i < 8; ++i) B[i] = *(const uint2*)(rp + (8 + i) * 256);
        #pragma unroll
        for (int i = 0; i < 8; ++i) STEP(A[i]);
        #pragma unroll
        for (int i = 0; i < 8; ++i) A[i] = *(const uint2*)(rp + (16 + i) * 256);
        #pragma unroll
        for (int i = 0; i < 8; ++i) STEP(B[i]);
        #pragma unroll
        for (int i = 0; i < 6; ++i) B[i] = *(const uint2*)(rp + (24 + i) * 256);
        #pragma unroll
        for (int i = 0; i < 8; ++i) STEP(A[i]);
        #pragma unroll
        for (int i = 0; i < 6; ++i) STEP(B[i]);
        // K[255][255] = lane 63's kup2 (col j = 4*63+2+1 = 255)
        if (lane == 63) atomicAdd(out, w * kup2);
    }
}

extern "C" void kernel_launch(void* const* d_in, const int* in_sizes, int n_in,
                              void* d_out, int out_size, void* d_ws, size_t ws_size,
                              hipStream_t stream) {
    const float* X = (const float*)d_in[0];
    const float* Y = (const float*)d_in[1];
    float* out = (float*)d_out;
    hipMemsetAsync(out, 0, sizeof(float), stream);
    sig_fused<<<dim3(3 * NA), dim3(256), 0, stream>>>(X, Y, out);
}